// Round 2
// baseline (251.971 us; speedup 1.0000x reference)
//
#include <hip/hip_runtime.h>
#include <hip/hip_bf16.h>

// AttentionBlock: B=16, N=2048, D=128, fp32 in/out.
// K1: bf16 MFMA projections eq/ek/ev(+transposed) + mask precompute.
// K2: flash-style attention, online softmax, 16x16x32 bf16 MFMA.

#define NEGBIG -4294967296.0f            // float32(-2^32+1) rounds to -2^32
#define SCALE  0.08838834764831845f      // 1/sqrt(128)

typedef __bf16 bf16x8 __attribute__((ext_vector_type(8)));
typedef float  f32x4  __attribute__((ext_vector_type(4)));

// ---------------- Kernel 1: projections + masks ----------------
// One block = 64 rows. Wave w handles 16 rows (row = base + w*16 + (lane&15)).
// A-frags live in registers; W (bf16) staged in LDS [128][136] (pad -> 2-way banks).
template<bool TP>
static __device__ __forceinline__ void do_proj(
    const float* __restrict__ W, const float* __restrict__ bias,
    const bf16x8 a[4], __bf16* __restrict__ dst,
    __bf16* Wl, __bf16* stage,
    int tid, int wave, int col, int quad, int rowbase)
{
    for (int i = tid; i < 128 * 128; i += 256)
        Wl[(i >> 7) * 136 + (i & 127)] = (__bf16)W[i];
    __syncthreads();

    f32x4 acc[8];
    #pragma unroll
    for (int ct = 0; ct < 8; ++ct) { f32x4 z = {0.f, 0.f, 0.f, 0.f}; acc[ct] = z; }
    #pragma unroll
    for (int f = 0; f < 4; ++f) {
        #pragma unroll
        for (int ct = 0; ct < 8; ++ct) {
            bf16x8 bfr = *(const bf16x8*)&Wl[(ct * 16 + col) * 136 + f * 32 + quad * 8];
            acc[ct] = __builtin_amdgcn_mfma_f32_16x16x32_bf16(a[f], bfr, acc[ct], 0, 0, 0);
        }
    }
    // C-layout: row = quad*4+r (A-row), col-of-tile = lane&15 (W-row = output d)
    #pragma unroll
    for (int ct = 0; ct < 8; ++ct) {
        float bv = bias[ct * 16 + col];
        #pragma unroll
        for (int r = 0; r < 4; ++r) {
            float v = acc[ct][r] + bv;
            if (TP) stage[(ct * 16 + col) * 72 + wave * 16 + quad * 4 + r] = (__bf16)v;   // [d][m]
            else    stage[(wave * 16 + quad * 4 + r) * 136 + ct * 16 + col] = (__bf16)v;  // [row][d]
        }
    }
    __syncthreads();
    if (!TP) {
        // rows contiguous in global: [row][128] bf16; stage stride 136 (272B, 16B-mult)
        int r = tid >> 2, seg = (tid & 3) * 32;                 // 64 rows x 4 threads x 64B
        uint4* g4 = (uint4*)(dst + (size_t)(rowbase + r) * 128 + seg);
        const uint4* s4 = (const uint4*)&stage[r * 136 + seg];
        g4[0] = s4[0]; g4[1] = s4[1]; g4[2] = s4[2]; g4[3] = s4[3];
    } else {
        // evT global layout [b][d][2048]; this block owns m-slice of 64
        int d = tid >> 1, mh = (tid & 1) * 32;
        int bb = rowbase >> 11, mb = rowbase & 2047;
        uint4* g4 = (uint4*)(dst + (size_t)bb * 128 * 2048 + (size_t)d * 2048 + mb + mh);
        const uint4* s4 = (const uint4*)&stage[d * 72 + mh];
        g4[0] = s4[0]; g4[1] = s4[1]; g4[2] = s4[2]; g4[3] = s4[3];
    }
    __syncthreads();
}

__global__ __launch_bounds__(256) void proj_kernel(
    const float* __restrict__ Q, const float* __restrict__ K,
    const int* __restrict__ PM,
    const float* __restrict__ Wq, const float* __restrict__ Bq,
    const float* __restrict__ Wk, const float* __restrict__ Bk,
    const float* __restrict__ Wv, const float* __restrict__ Bv,
    __bf16* __restrict__ eqb, __bf16* __restrict__ ekb, __bf16* __restrict__ evT,
    float* __restrict__ ksel, float* __restrict__ kovr, float* __restrict__ qpad)
{
    __shared__ __bf16 Wl[128 * 136];
    __shared__ __bf16 stage[128 * 72];   // also reused as [64][136] for eq/ek (8704 <= 9216)
    const int tid  = threadIdx.x;
    const int wave = tid >> 6, lane = tid & 63;
    const int col  = lane & 15, quad = lane >> 4;
    const int rowbase = blockIdx.x * 64;
    const int myrow   = rowbase + wave * 16 + col;

    // A-frags (fp32 -> bf16) + exact fp32 row sums for the masks
    bf16x8 aq[4], ak[4];
    float qs = 0.f, kss = 0.f;
    #pragma unroll
    for (int f = 0; f < 4; ++f) {
        const float* pq = Q + (size_t)myrow * 128 + f * 32 + quad * 8;
        const float* pk = K + (size_t)myrow * 128 + f * 32 + quad * 8;
        float4 q0 = *(const float4*)pq, q1 = *(const float4*)(pq + 4);
        float4 k0 = *(const float4*)pk, k1 = *(const float4*)(pk + 4);
        float qv[8] = {q0.x, q0.y, q0.z, q0.w, q1.x, q1.y, q1.z, q1.w};
        float kv[8] = {k0.x, k0.y, k0.z, k0.w, k1.x, k1.y, k1.z, k1.w};
        #pragma unroll
        for (int j = 0; j < 8; ++j) {
            qs += qv[j]; kss += kv[j];
            aq[f][j] = (__bf16)qv[j];
            ak[f][j] = (__bf16)kv[j];
        }
    }
    // full-row sums: reduce across the 4 lanes sharing (lane&15)
    qs  += __shfl_xor(qs, 16);  qs  += __shfl_xor(qs, 32);
    kss += __shfl_xor(kss, 16); kss += __shfl_xor(kss, 32);
    if (quad == 0) {
        qpad[myrow] = (qs != 0.f) ? 1.f : 0.f;
        int pmv = PM[myrow];
        ksel[myrow] = (pmv != 0) ? 1.f : 0.f;
        kovr[myrow] = (pmv != 0) ? 0.f : ((kss == 0.f) ? NEGBIG : 0.f);
    }
    __syncthreads();

    do_proj<false>(Wq, Bq, aq, eqb, Wl, stage, tid, wave, col, quad, rowbase);
    do_proj<false>(Wk, Bk, ak, ekb, Wl, stage, tid, wave, col, quad, rowbase);
    do_proj<true >(Wv, Bv, ak, evT, Wl, stage, tid, wave, col, quad, rowbase);
}

// ---------------- Kernel 2: flash attention ----------------
// Block: 4 waves, 128 q-rows (wave owns 32 = 2 subtiles of 16). Key tiles of 64.
// Grid MUST be 256: 16 batches x (2048/128 = 16 q-tiles).  (R0 crash: 512.)
__global__ __launch_bounds__(256, 2) void attn_kernel(
    const __bf16* __restrict__ eqb, const __bf16* __restrict__ ekb,
    const __bf16* __restrict__ evT,
    const float* __restrict__ ksel, const float* __restrict__ kovr,
    const float* __restrict__ qpad,
    const float* __restrict__ Q, float* __restrict__ out)
{
    __shared__ __bf16 ekt[64 * 136];     // [m][k] stride 136
    __shared__ __bf16 evt[128 * 72];     // [d][m] stride 72
    __shared__ __bf16 pt[4][32 * 72];    // per-wave P strip [q][m] stride 72

    const int tid  = threadIdx.x;
    const int wave = tid >> 6, lane = tid & 63;
    const int col  = lane & 15, quad = lane >> 4;
    const int b  = blockIdx.x & 15;            // 16 batches
    const int qt = blockIdx.x >> 4;            // 16 q-tiles of 128 rows
    const int rowg0 = b * 2048 + qt * 128 + wave * 32;

    bf16x8 aqf[2][4];
    #pragma unroll
    for (int qs = 0; qs < 2; ++qs)
        #pragma unroll
        for (int f = 0; f < 4; ++f)
            aqf[qs][f] = *(const bf16x8*)&eqb[(size_t)(rowg0 + qs * 16 + col) * 128 + f * 32 + quad * 8];

    f32x4 o[2][8];
    float mold[2][4], lsum[2][4];
    #pragma unroll
    for (int qs = 0; qs < 2; ++qs) {
        #pragma unroll
        for (int dt = 0; dt < 8; ++dt) { f32x4 z = {0.f, 0.f, 0.f, 0.f}; o[qs][dt] = z; }
        #pragma unroll
        for (int r = 0; r < 4; ++r) { mold[qs][r] = -1e30f; lsum[qs][r] = 0.f; }
    }

    for (int it = 0; it < 32; ++it) {
        const int mbase = it * 64;
        // stage K tile (64x128 bf16, 16KB) and V^T tile (128x64 bf16, 16KB)
        const uint4* gk = (const uint4*)(ekb + (size_t)(b * 2048 + mbase) * 128);
        #pragma unroll
        for (int i = 0; i < 4; ++i) {
            int j = tid + i * 256;
            *(uint4*)&ekt[(j >> 4) * 136 + (j & 15) * 8] = gk[j];
        }
        const __bf16* gv = evT + (size_t)b * 128 * 2048 + mbase;
        #pragma unroll
        for (int i = 0; i < 4; ++i) {
            int j = tid + i * 256;
            *(uint4*)&evt[(j >> 3) * 72 + (j & 7) * 8] =
                *(const uint4*)(gv + (size_t)(j >> 3) * 2048 + (j & 7) * 8);
        }
        __syncthreads();

        // S = eq @ ek^T  (C-layout: row=q=quad*4+r, col-of-tile=m=lane&15)
        f32x4 s[2][4];
        #pragma unroll
        for (int qs = 0; qs < 2; ++qs)
            #pragma unroll
            for (int mt = 0; mt < 4; ++mt) { f32x4 z = {0.f, 0.f, 0.f, 0.f}; s[qs][mt] = z; }
        #pragma unroll
        for (int f = 0; f < 4; ++f) {
            bf16x8 bfr[4];
            #pragma unroll
            for (int mt = 0; mt < 4; ++mt)
                bfr[mt] = *(const bf16x8*)&ekt[(mt * 16 + col) * 136 + f * 32 + quad * 8];
            #pragma unroll
            for (int qs = 0; qs < 2; ++qs)
                #pragma unroll
                for (int mt = 0; mt < 4; ++mt)
                    s[qs][mt] = __builtin_amdgcn_mfma_f32_16x16x32_bf16(aqf[qs][f], bfr[mt], s[qs][mt], 0, 0, 0);
        }

        // mask + scale: s = coefs*scale*sel + ovr  (sel=0 -> constant 0 or NEG)
        float msel[4], movr[4], qpd[4];
        #pragma unroll
        for (int mt = 0; mt < 4; ++mt) {
            int m = b * 2048 + mbase + mt * 16 + col;
            msel[mt] = ksel[m] * SCALE;
            movr[mt] = kovr[m];
            qpd[mt]  = qpad[m];
        }
        #pragma unroll
        for (int qs = 0; qs < 2; ++qs)
            #pragma unroll
            for (int mt = 0; mt < 4; ++mt)
                #pragma unroll
                for (int r = 0; r < 4; ++r)
                    s[qs][mt][r] = s[qs][mt][r] * msel[mt] + movr[mt];

        // online softmax (row stats per quad via shfl_xor 1,2,4,8 — stays in-quad)
        #pragma unroll
        for (int qs = 0; qs < 2; ++qs) {
            #pragma unroll
            for (int r = 0; r < 4; ++r) {
                float v = fmaxf(fmaxf(s[qs][0][r], s[qs][1][r]), fmaxf(s[qs][2][r], s[qs][3][r]));
                v = fmaxf(v, __shfl_xor(v, 1));
                v = fmaxf(v, __shfl_xor(v, 2));
                v = fmaxf(v, __shfl_xor(v, 4));
                v = fmaxf(v, __shfl_xor(v, 8));
                float mnew  = fmaxf(mold[qs][r], v);
                float alpha = __expf(mold[qs][r] - mnew);
                mold[qs][r] = mnew;
                float ts = 0.f;
                #pragma unroll
                for (int mt = 0; mt < 4; ++mt) {
                    float e = __expf(s[qs][mt][r] - mnew);
                    s[qs][mt][r] = e;
                    ts += e;
                }
                ts += __shfl_xor(ts, 1);
                ts += __shfl_xor(ts, 2);
                ts += __shfl_xor(ts, 4);
                ts += __shfl_xor(ts, 8);
                lsum[qs][r] = lsum[qs][r] * alpha + ts;
                #pragma unroll
                for (int dt = 0; dt < 8; ++dt) o[qs][dt][r] *= alpha;
            }
            // P (with the faithful q_pad-along-key-axis multiply) -> LDS, A-operand order
            #pragma unroll
            for (int mt = 0; mt < 4; ++mt)
                #pragma unroll
                for (int r = 0; r < 4; ++r)
                    pt[wave][(qs * 16 + quad * 4 + r) * 72 + mt * 16 + col] =
                        (__bf16)(s[qs][mt][r] * qpd[mt]);
        }

        // O += P @ ev   (B-operand rows are evT's d-rows, k = m)
        #pragma unroll
        for (int ks = 0; ks < 2; ++ks) {
            bf16x8 pa[2];
            #pragma unroll
            for (int qs = 0; qs < 2; ++qs)
                pa[qs] = *(const bf16x8*)&pt[wave][(qs * 16 + col) * 72 + ks * 32 + quad * 8];
            #pragma unroll
            for (int dt = 0; dt < 8; ++dt) {
                bf16x8 bv = *(const bf16x8*)&evt[(dt * 16 + col) * 72 + ks * 32 + quad * 8];
                #pragma unroll
                for (int qs = 0; qs < 2; ++qs)
                    o[qs][dt] = __builtin_amdgcn_mfma_f32_16x16x32_bf16(pa[qs], bv, o[qs][dt], 0, 0, 0);
            }
        }
        __syncthreads();
    }

    // epilogue: normalize by l, add residual queries (fp32), store fp32
    #pragma unroll
    for (int qs = 0; qs < 2; ++qs) {
        float inv[4];
        #pragma unroll
        for (int r = 0; r < 4; ++r) inv[r] = 1.f / lsum[qs][r];
        #pragma unroll
        for (int dt = 0; dt < 8; ++dt)
            #pragma unroll
            for (int r = 0; r < 4; ++r) {
                size_t idx = (size_t)(rowg0 + qs * 16 + quad * 4 + r) * 128 + dt * 16 + col;
                out[idx] = o[qs][dt][r] * inv[r] + Q[idx];
            }
    }
}

extern "C" void kernel_launch(void* const* d_in, const int* in_sizes, int n_in,
                              void* d_out, int out_size, void* d_ws, size_t ws_size,
                              hipStream_t stream)
{
    const float* Q  = (const float*)d_in[0];
    const float* K  = (const float*)d_in[1];
    const int*   PM = (const int*)d_in[2];
    const float* Wq = (const float*)d_in[3];
    const float* Bq = (const float*)d_in[4];
    const float* Wk = (const float*)d_in[5];
    const float* Bk = (const float*)d_in[6];
    const float* Wv = (const float*)d_in[7];
    const float* Bv = (const float*)d_in[8];
    float* out = (float*)d_out;

    const size_t SZE = (size_t)16 * 2048 * 128;     // 4,194,304 elements
    __bf16* eqb = (__bf16*)d_ws;                    // 8 MB
    __bf16* ekb = eqb + SZE;                        // 8 MB
    __bf16* evT = ekb + SZE;                        // 8 MB, layout [B][D][N]
    float* ksel = (float*)(evT + SZE);              // 128 KB each
    float* kovr = ksel + 16 * 2048;
    float* qpad = kovr + 16 * 2048;

    proj_kernel<<<512, 256, 0, stream>>>(Q, K, PM, Wq, Bq, Wk, Bk, Wv, Bv,
                                         eqb, ekb, evT, ksel, kovr, qpad);
    attn_kernel<<<256, 256, 0, stream>>>(eqb, ekb, evT, ksel, kovr, qpad, Q, out);
}